// Round 5
// baseline (405.906 us; speedup 1.0000x reference)
//
#include <hip/hip_runtime.h>
#include <math.h>

#define BDIM 512
#define DDIM 512

constexpr float EPS   = 1e-6f;
constexpr float HEPS  = 0.5e-6f;
constexpr float LN2   = 0.6931471805599453f;
constexpr float LOG2E = 1.4426950408889634f;

__device__ __forceinline__ float wave_reduce_sum(float v) {
  #pragma unroll
  for (int o = 32; o > 0; o >>= 1) v += __shfl_down(v, o, 64);
  return v;
}
__device__ __forceinline__ float wave_reduce_max(float v) {
  #pragma unroll
  for (int o = 32; o > 0; o >>= 1) v = fmaxf(v, __shfl_down(v, o, 64));
  return v;
}

// ---------------------------------------------------------------------------
// Kernel 1: per-row l2-normalize mu; emit interleaved pairs
// pX[r][d] = (n, 0.5*sigma + 0.5*EPS)  so that bd's sv = A.y + B.y.
// Also ld[r] = sum_d ln(sigma+EPS), mrow[r] = mean sigma.
// ---------------------------------------------------------------------------
__global__ __launch_bounds__(256) void prep_kernel(
    const float* __restrict__ mu1, const float* __restrict__ s1,
    const float* __restrict__ mu2, const float* __restrict__ s2,
    float2* __restrict__ pA, float2* __restrict__ pB,
    float* __restrict__ ld,         // ld1 at 0, ld2 at +B
    float* __restrict__ mrow) {     // m1 at 0, m2 at +B
  const int r = blockIdx.x;
  const int which = blockIdx.y;
  const float* __restrict__ mu = which ? mu2 : mu1;
  const float* __restrict__ sg = which ? s2 : s1;
  float2* __restrict__ pout = which ? pB : pA;
  const int t = threadIdx.x;

  const float a  = mu[r * DDIM + t];
  const float b  = mu[r * DDIM + t + 256];
  const float sa = sg[r * DDIM + t];
  const float sb = sg[r * DDIM + t + 256];

  float v0 = a * a + b * b;
  float v1 = __log2f(sa + EPS) + __log2f(sb + EPS);
  float v2 = sa + sb;

  __shared__ float red[3][4];
  __shared__ float sinv;
  const int wid = t >> 6, lane = t & 63;
  v0 = wave_reduce_sum(v0);
  v1 = wave_reduce_sum(v1);
  v2 = wave_reduce_sum(v2);
  if (lane == 0) { red[0][wid] = v0; red[1][wid] = v1; red[2][wid] = v2; }
  __syncthreads();
  if (t == 0) {
    float sq = red[0][0] + red[0][1] + red[0][2] + red[0][3];
    float lg = red[1][0] + red[1][1] + red[1][2] + red[1][3];
    float sm = red[2][0] + red[2][1] + red[2][2] + red[2][3];
    ld[which * BDIM + r]   = LN2 * lg;
    mrow[which * BDIM + r] = sm * (1.0f / DDIM);
    sinv = 1.0f / fmaxf(sqrtf(sq), 1e-12f);
  }
  __syncthreads();
  const float inv = sinv;
  pout[r * DDIM + t]       = make_float2(a * inv, fmaf(0.5f, sa, HEPS));
  pout[r * DDIM + t + 256] = make_float2(b * inv, fmaf(0.5f, sb, HEPS));
}

// ---------------------------------------------------------------------------
// Kernel 2: B^2*D partial pass — R2 structure + D-split for 2 blocks/CU.
// Grid (16,16,2), block 1024 = 4 groups of 4 waves. Each group owns a
// 64-d slice of z's 256-d half, staged to its private LDS region in 4
// chunks of 16 d (2 barriers/chunk). 2x2 register blocking -> VGPR 64 =
// exactly the 8-wave/SIMD cap (enforced) so two blocks co-reside and
// fill each other's barrier stalls. log2 over products of 8.
// Output: float2-packed partials per z-plane; combine_kernel finishes.
// ---------------------------------------------------------------------------
#define TROW 17                     // pairs per LDS row (16 + 1 pad)
#define GTILE (2 * 32 * TROW)       // float2 per group (A + B)

__global__ __launch_bounds__(1024, 8) void bd_kernel(
    const float2* __restrict__ pA, const float2* __restrict__ pB,
    float* __restrict__ t1p, float* __restrict__ ldap,
    float* __restrict__ dacp) {
  // max(tiles: 4*GTILE*8B = 34816B, combine: 3*256*13*4B = 39936B)
  __shared__ __align__(16) float smem[9984];

  const int t   = threadIdx.x;
  const int grp = t >> 8;          // 0..3 (64-d sub-slice)
  const int lt  = t & 255;         // lane in group
  const int i0 = blockIdx.y * 32, j0 = blockIdx.x * 32;
  const int z  = blockIdx.z;       // 0..1 (256-d half)
  const int il = (lt >> 4) * 2;    // 0..30 step 2
  const int jl = (lt & 15) * 2;

  float2* tA = (float2*)smem + grp * GTILE;
  float2* tB = tA + 32 * TROW;

  float t1[2][2]  = {{0.f,0.f},{0.f,0.f}};
  float lda[2][2] = {{0.f,0.f},{0.f,0.f}};
  float dac[2][2] = {{0.f,0.f},{0.f,0.f}};

  const float2* a0p = tA + il * TROW;
  const float2* a1p = tA + (il + 1) * TROW;
  const float2* b0p = tB + jl * TROW;
  const float2* b1p = tB + (jl + 1) * TROW;

  const int dbase = z * 256 + grp * 64;
  for (int c = 0; c < 4; ++c) {
    const int d0 = dbase + c * 16;
    __syncthreads();
    // stage this group's 16-d chunk: 2 arrays x 32 rows x 8 float4 = 512
    // float4 loads; 256 threads -> 2 each (one from A, one from B).
    {
      int f = lt;
      #pragma unroll
      for (int q = 0; q < 2; ++q, f += 256) {
        const int arr = f >> 8;          // 0 -> A, 1 -> B
        const int row = (f >> 3) & 31;
        const int dq  = (f & 7) * 2;     // even pair index in chunk
        const float2* __restrict__ src = arr ? pB : pA;
        const int grow = (arr ? j0 : i0) + row;
        const float4 v = *(const float4*)&src[grow * DDIM + d0 + dq];
        float2* dst = (arr ? tB : tA) + row * TROW + dq;
        dst[0] = make_float2(v.x, v.y);
        dst[1] = make_float2(v.z, v.w);
      }
    }
    __syncthreads();
    #pragma unroll
    for (int g8 = 0; g8 < 2; ++g8) {
      float m[2][2] = {{1.f,1.f},{1.f,1.f}};
      #pragma unroll
      for (int k = 0; k < 8; ++k) {
        const int d = g8 * 8 + k;
        const float2 A0 = a0p[d], A1 = a1p[d];
        const float2 B0 = b0p[d], B1 = b1p[d];
        #define UPD(ii, jj, Av, Bv)                                          \
          {                                                                  \
            const float sv = Av.y + Bv.y;                                    \
            const float df = Av.x - Bv.x;                                    \
            t1[ii][jj] = fmaf(df * df, __builtin_amdgcn_rcpf(sv), t1[ii][jj]);\
            m[ii][jj] *= sv;                                                 \
            dac[ii][jj] = fmaf(Av.x, Bv.x, dac[ii][jj]);                     \
          }
        UPD(0, 0, A0, B0) UPD(0, 1, A0, B1)
        UPD(1, 0, A1, B0) UPD(1, 1, A1, B1)
        #undef UPD
      }
      lda[0][0] += __log2f(m[0][0]);
      lda[0][1] += __log2f(m[0][1]);
      lda[1][0] += __log2f(m[1][0]);
      lda[1][1] += __log2f(m[1][1]);
    }
  }
  __syncthreads();

  // cross-group combine: groups 1..3 write 12 partials, group 0 reduces,
  // then writes float2-packed partials for this z-plane.
  if (grp > 0) {
    float* p = smem + ((grp - 1) * 256 + lt) * 13;
    p[0] = t1[0][0];  p[1] = t1[0][1];  p[2]  = t1[1][0];  p[3]  = t1[1][1];
    p[4] = lda[0][0]; p[5] = lda[0][1]; p[6]  = lda[1][0]; p[7]  = lda[1][1];
    p[8] = dac[0][0]; p[9] = dac[0][1]; p[10] = dac[1][0]; p[11] = dac[1][1];
  }
  __syncthreads();
  if (grp == 0) {
    #pragma unroll
    for (int g = 0; g < 3; ++g) {
      const float* p = smem + (g * 256 + lt) * 13;
      t1[0][0]  += p[0]; t1[0][1]  += p[1]; t1[1][0]  += p[2];  t1[1][1]  += p[3];
      lda[0][0] += p[4]; lda[0][1] += p[5]; lda[1][0] += p[6];  lda[1][1] += p[7];
      dac[0][0] += p[8]; dac[0][1] += p[9]; dac[1][0] += p[10]; dac[1][1] += p[11];
    }
    const size_t zb = (size_t)z * BDIM * BDIM;
    #pragma unroll
    for (int ii = 0; ii < 2; ++ii) {
      const size_t o = zb + (size_t)(i0 + il + ii) * BDIM + j0 + jl;
      *(float2*)&t1p[o]  = make_float2(t1[ii][0],  t1[ii][1]);
      *(float2*)&ldap[o] = make_float2(lda[ii][0], lda[ii][1]);
      *(float2*)&dacp[o] = make_float2(dac[ii][0], dac[ii][1]);
    }
  }
}

// ---------------------------------------------------------------------------
// Kernel 3: combine z-partials -> sim, pdiag, per-row off-diag max (no atomics)
// ---------------------------------------------------------------------------
__global__ __launch_bounds__(256) void combine_kernel(
    const float* __restrict__ t1p, const float* __restrict__ ldap,
    const float* __restrict__ dacp, const float* __restrict__ ld,
    float* __restrict__ sim, float* __restrict__ pmaxf,
    float* __restrict__ pdiag) {
  const int i = blockIdx.x;
  const int t = threadIdx.x;
  const float l1 = ld[i];
  float rmax = 0.f;
  #pragma unroll
  for (int q = 0; q < 2; ++q) {
    const int j = t + q * 256;
    const size_t o = (size_t)i * BDIM + j;
    float t1 = 0.f, lda = 0.f, dac = 0.f;
    #pragma unroll
    for (int zz = 0; zz < 2; ++zz) {
      const size_t idx = (size_t)zz * BDIM * BDIM + o;
      t1 += t1p[idx]; lda += ldap[idx]; dac += dacp[idx];
    }
    const float bd = fmaf(0.125f, t1,
                          0.5f * (LN2 * lda - 0.5f * (l1 + ld[BDIM + j])));
    sim[o] = exp2f(bd * (-LOG2E / (float)DDIM));
    const float p = exp2f((2.0f * LOG2E) * dac);
    if (j == i) pdiag[i] = p;
    else        rmax = fmaxf(rmax, p);
  }
  __shared__ float red[4];
  const int wid = t >> 6, lane = t & 63;
  const float wm = wave_reduce_max(rmax);
  if (lane == 0) red[wid] = wm;
  __syncthreads();
  if (t == 0) pmaxf[i] = fmaxf(fmaxf(red[0], red[1]), fmaxf(red[2], red[3]));
}

// ---------------------------------------------------------------------------
// Kernel 4: per-row and per-column LSE of logits = scale*sim, plus diag.
// ---------------------------------------------------------------------------
__global__ __launch_bounds__(256) void lse_kernel(
    const float* __restrict__ sim, const float* __restrict__ lscale,
    float* __restrict__ lse_row, float* __restrict__ lse_col,
    float* __restrict__ dlog) {
  const int b = blockIdx.x;
  const int t = threadIdx.x;
  const float sc = *lscale;
  const float r0 = sc * sim[b * BDIM + t];
  const float r1 = sc * sim[b * BDIM + t + 256];
  const float c0 = sc * sim[t * BDIM + b];
  const float c1 = sc * sim[(t + 256) * BDIM + b];

  __shared__ float red[4];
  const int wid = t >> 6, lane = t & 63;

  float rm = wave_reduce_max(fmaxf(r0, r1));
  if (lane == 0) red[wid] = rm;
  __syncthreads();
  rm = fmaxf(fmaxf(red[0], red[1]), fmaxf(red[2], red[3]));
  __syncthreads();

  float cm = wave_reduce_max(fmaxf(c0, c1));
  if (lane == 0) red[wid] = cm;
  __syncthreads();
  cm = fmaxf(fmaxf(red[0], red[1]), fmaxf(red[2], red[3]));
  __syncthreads();

  float rs = wave_reduce_sum(exp2f((r0 - rm) * LOG2E) + exp2f((r1 - rm) * LOG2E));
  if (lane == 0) red[wid] = rs;
  __syncthreads();
  rs = red[0] + red[1] + red[2] + red[3];
  __syncthreads();

  float cs = wave_reduce_sum(exp2f((c0 - cm) * LOG2E) + exp2f((c1 - cm) * LOG2E));
  if (lane == 0) red[wid] = cs;
  __syncthreads();
  cs = red[0] + red[1] + red[2] + red[3];

  if (t == 0) {
    lse_row[b] = rm + LN2 * __log2f(rs);
    lse_col[b] = cm + LN2 * __log2f(cs);
    dlog[b]    = sc * sim[b * BDIM + b];
  }
}

// ---------------------------------------------------------------------------
// Kernel 5: final reductions -> 3 scalars.
// ---------------------------------------------------------------------------
__global__ __launch_bounds__(512) void final_kernel(
    const float* __restrict__ pdiag, const float* __restrict__ pmaxf,
    const float* __restrict__ mrow, const float* __restrict__ lse_row,
    const float* __restrict__ lse_col, const float* __restrict__ dlog,
    float* __restrict__ out) {
  const int t = threadIdx.x;  // 0..511
  const float pm = pmaxf[t];
  const float u  = exp2f(-(pdiag[t] / pm) * LOG2E);   // exp(-diag/negmax)
  const float as = 0.5f * (mrow[t] + mrow[BDIM + t]);

  float vals[6];
  vals[0] = u;
  vals[1] = u * u;
  vals[2] = as * as;
  vals[3] = u * as;
  vals[4] = lse_row[t] - dlog[t];
  vals[5] = lse_col[t] - dlog[t];

  __shared__ float red[6][8];
  const int wid = t >> 6, lane = t & 63;
  #pragma unroll
  for (int k = 0; k < 6; ++k) {
    const float v = wave_reduce_sum(vals[k]);
    if (lane == 0) red[k][wid] = v;
  }
  __syncthreads();
  if (t == 0) {
    float s[6];
    #pragma unroll
    for (int k = 0; k < 6; ++k) {
      float a = 0.f;
      #pragma unroll
      for (int w = 0; w < 8; ++w) a += red[k][w];
      s[k] = a;
    }
    const float mean_u = s[0] * (1.0f / BDIM);
    const float cosv = s[3] / fmaxf(sqrtf(s[1]) * sqrtf(s[2]), 1e-24f);
    out[0] = 0.5f * (s[4] + s[5]) * (1.0f / BDIM);  // loss_pro
    out[1] = 2.4f * (1.0f - cosv);                  // loss_rank * 2.4
    out[2] = 0.5f * mean_u;                         // var_loss
  }
}

extern "C" void kernel_launch(void* const* d_in, const int* in_sizes, int n_in,
                              void* d_out, int out_size, void* d_ws, size_t ws_size,
                              hipStream_t stream) {
  const float* mu1 = (const float*)d_in[0];
  const float* s1  = (const float*)d_in[1];
  const float* mu2 = (const float*)d_in[2];
  const float* s2  = (const float*)d_in[3];
  const float* lsc = (const float*)d_in[4];
  float* out = (float*)d_out;

  float* ws      = (float*)d_ws;
  float2* pA     = (float2*)ws;                       // 512*512 float2 (2MB)
  float2* pB     = pA + BDIM * DDIM;                  // 2MB
  float* sim     = (float*)(pB + BDIM * DDIM);        // 1MB
  float* t1p     = sim + BDIM * BDIM;                 // 2 * 1MB
  float* ldap    = t1p + 2 * BDIM * BDIM;             // 2 * 1MB
  float* dacp    = ldap + 2 * BDIM * BDIM;            // 2 * 1MB
  float* ld      = dacp + 2 * BDIM * BDIM;            // 2*512
  float* mrow    = ld + 2 * BDIM;                     // 2*512
  float* pmaxf   = mrow + 2 * BDIM;                   // 512
  float* pdiag   = pmaxf + BDIM;                      // 512
  float* lse_row = pdiag + BDIM;                      // 512
  float* lse_col = lse_row + BDIM;                    // 512
  float* dlog    = lse_col + BDIM;                    // 512

  prep_kernel<<<dim3(BDIM, 2), 256, 0, stream>>>(mu1, s1, mu2, s2, pA, pB,
                                                 ld, mrow);
  bd_kernel<<<dim3(16, 16, 2), 1024, 0, stream>>>(pA, pB, t1p, ldap, dacp);
  combine_kernel<<<BDIM, 256, 0, stream>>>(t1p, ldap, dacp, ld, sim, pmaxf,
                                           pdiag);
  lse_kernel<<<BDIM, 256, 0, stream>>>(sim, lsc, lse_row, lse_col, dlog);
  final_kernel<<<1, 512, 0, stream>>>(pdiag, pmaxf, mrow, lse_row, lse_col,
                                      dlog, out);
}

// Round 6
// 54.217 us; speedup vs baseline: 7.4867x; 7.4867x over previous
//
#include <hip/hip_runtime.h>
#include <math.h>

#define BDIM 512
#define DDIM 512

constexpr float EPS   = 1e-6f;
constexpr float HEPS  = 0.5e-6f;
constexpr float LN2   = 0.6931471805599453f;
constexpr float LOG2E = 1.4426950408889634f;

__device__ __forceinline__ float wave_reduce_sum(float v) {
  #pragma unroll
  for (int o = 32; o > 0; o >>= 1) v += __shfl_down(v, o, 64);
  return v;
}
__device__ __forceinline__ float wave_reduce_max(float v) {
  #pragma unroll
  for (int o = 32; o > 0; o >>= 1) v = fmaxf(v, __shfl_down(v, o, 64));
  return v;
}

// ---------------------------------------------------------------------------
// Kernel 1: per-row l2-normalize mu; emit interleaved pairs
// pX[r][d] = (n, 0.5*sigma + 0.5*EPS)  so that bd's sv = A.y + B.y.
// Also ld[r] = sum_d ln(sigma+EPS), mrow[r] = mean sigma.
// ---------------------------------------------------------------------------
__global__ __launch_bounds__(256) void prep_kernel(
    const float* __restrict__ mu1, const float* __restrict__ s1,
    const float* __restrict__ mu2, const float* __restrict__ s2,
    float2* __restrict__ pA, float2* __restrict__ pB,
    float* __restrict__ ld,         // ld1 at 0, ld2 at +B
    float* __restrict__ mrow) {     // m1 at 0, m2 at +B
  const int r = blockIdx.x;
  const int which = blockIdx.y;
  const float* __restrict__ mu = which ? mu2 : mu1;
  const float* __restrict__ sg = which ? s2 : s1;
  float2* __restrict__ pout = which ? pB : pA;
  const int t = threadIdx.x;

  const float a  = mu[r * DDIM + t];
  const float b  = mu[r * DDIM + t + 256];
  const float sa = sg[r * DDIM + t];
  const float sb = sg[r * DDIM + t + 256];

  float v0 = a * a + b * b;
  float v1 = __log2f(sa + EPS) + __log2f(sb + EPS);
  float v2 = sa + sb;

  __shared__ float red[3][4];
  __shared__ float sinv;
  const int wid = t >> 6, lane = t & 63;
  v0 = wave_reduce_sum(v0);
  v1 = wave_reduce_sum(v1);
  v2 = wave_reduce_sum(v2);
  if (lane == 0) { red[0][wid] = v0; red[1][wid] = v1; red[2][wid] = v2; }
  __syncthreads();
  if (t == 0) {
    float sq = red[0][0] + red[0][1] + red[0][2] + red[0][3];
    float lg = red[1][0] + red[1][1] + red[1][2] + red[1][3];
    float sm = red[2][0] + red[2][1] + red[2][2] + red[2][3];
    ld[which * BDIM + r]   = LN2 * lg;
    mrow[which * BDIM + r] = sm * (1.0f / DDIM);
    sinv = 1.0f / fmaxf(sqrtf(sq), 1e-12f);
  }
  __syncthreads();
  const float inv = sinv;
  pout[r * DDIM + t]       = make_float2(a * inv, fmaf(0.5f, sa, HEPS));
  pout[r * DDIM + t + 256] = make_float2(b * inv, fmaf(0.5f, sb, HEPS));
}

// ---------------------------------------------------------------------------
// Kernel 2: B^2*D partial pass — stage ONCE, zero main-loop barriers.
// Grid (16,16,2), block 1024 = 4 groups of 4 waves. Block covers the 256-d
// half z; group g owns d-slice [g*64, g*64+64), staged whole to LDS
// (2 arrays x 32 rows x 64 pairs, row stride 65 pairs -> 2-way bank
// aliasing = free). One sync after staging, then 64 d-steps of pure
// LDS+VALU compute per group (2x2 per lane, log2 over products of 8).
// Tail: 3-barrier LDS partial combine (overlays tile memory), wave-group 0
// writes float2-packed partials per z-plane. NO launch-bounds minimum —
// R3/R4/R5 showed it halves the VGPR budget and spills.
// LDS = 4 groups * 4160 float2 = 133120 B <= 160 KiB (1 block/CU).
// ---------------------------------------------------------------------------
#define GSTRIDE 65                      // pairs per row (64 + 1 pad)
#define GHALF   (32 * GSTRIDE)          // float2 per array per group (2080)
#define GTILE   (2 * GHALF)             // float2 per group (4160)

__global__ __launch_bounds__(1024) void bd_kernel(
    const float2* __restrict__ pA, const float2* __restrict__ pB,
    float* __restrict__ t1p, float* __restrict__ ldap,
    float* __restrict__ dacp) {
  __shared__ __align__(16) float smem[4 * GTILE * 2];   // 133120 B

  const int t   = threadIdx.x;
  const int grp = t >> 8;          // 0..3 (64-d sub-slice)
  const int lt  = t & 255;         // lane in group
  const int i0 = blockIdx.y * 32, j0 = blockIdx.x * 32;
  const int z  = blockIdx.z;       // 0..1 (256-d half)
  const int il = (lt >> 4) * 2;    // 0..30 step 2
  const int jl = (lt & 15) * 2;

  float2* tile = (float2*)smem;

  // ---- stage the whole 256-d half: 8192 float4 loads, 8 per thread ----
  {
    #pragma unroll
    for (int q = 0; q < 8; ++q) {
      const int idx = q * 1024 + t;       // 0..8191
      const int arr = idx >> 12;          // 0 -> A, 1 -> B
      const int rem = idx & 4095;
      const int row = rem >> 7;           // 0..31
      const int c4  = rem & 127;          // float4 index within row
      const float2* __restrict__ src = arr ? pB : pA;
      const int grow = (arr ? j0 : i0) + row;
      const float4 v = *(const float4*)&src[grow * DDIM + z * 256 + c4 * 2];
      const int p = c4 * 2;               // pair index 0..254 (even)
      const int g = p >> 6;               // target group
      const int d = p & 63;               // pair within group slice
      float2* dst = tile + g * GTILE + arr * GHALF + row * GSTRIDE + d;
      dst[0] = make_float2(v.x, v.y);
      dst[1] = make_float2(v.z, v.w);
    }
  }
  __syncthreads();

  // ---- barrier-free main loop: 64 d-steps from this group's LDS slice ----
  float t1[2][2]  = {{0.f,0.f},{0.f,0.f}};
  float lda[2][2] = {{0.f,0.f},{0.f,0.f}};
  float dac[2][2] = {{0.f,0.f},{0.f,0.f}};

  const float2* gbase = tile + grp * GTILE;
  const float2* a0p = gbase + il * GSTRIDE;
  const float2* a1p = gbase + (il + 1) * GSTRIDE;
  const float2* b0p = gbase + GHALF + jl * GSTRIDE;
  const float2* b1p = gbase + GHALF + (jl + 1) * GSTRIDE;

  for (int g8 = 0; g8 < 8; ++g8) {
    float m[2][2] = {{1.f,1.f},{1.f,1.f}};
    #pragma unroll
    for (int k = 0; k < 8; ++k) {
      const int d = g8 * 8 + k;
      const float2 A0 = a0p[d], A1 = a1p[d];
      const float2 B0 = b0p[d], B1 = b1p[d];
      #define UPD(ii, jj, Av, Bv)                                            \
        {                                                                    \
          const float sv = Av.y + Bv.y;                                      \
          const float df = Av.x - Bv.x;                                      \
          t1[ii][jj] = fmaf(df * df, __builtin_amdgcn_rcpf(sv), t1[ii][jj]); \
          m[ii][jj] *= sv;                                                   \
          dac[ii][jj] = fmaf(Av.x, Bv.x, dac[ii][jj]);                       \
        }
      UPD(0, 0, A0, B0) UPD(0, 1, A0, B1)
      UPD(1, 0, A1, B0) UPD(1, 1, A1, B1)
      #undef UPD
    }
    lda[0][0] += __log2f(m[0][0]);
    lda[0][1] += __log2f(m[0][1]);
    lda[1][0] += __log2f(m[1][0]);
    lda[1][1] += __log2f(m[1][1]);
  }

  // ---- cross-group combine (overlays tile LDS; compute is done) ----
  __syncthreads();
  if (grp > 0) {
    float* p = smem + ((grp - 1) * 256 + lt) * 13;
    p[0] = t1[0][0];  p[1] = t1[0][1];  p[2]  = t1[1][0];  p[3]  = t1[1][1];
    p[4] = lda[0][0]; p[5] = lda[0][1]; p[6]  = lda[1][0]; p[7]  = lda[1][1];
    p[8] = dac[0][0]; p[9] = dac[0][1]; p[10] = dac[1][0]; p[11] = dac[1][1];
  }
  __syncthreads();
  if (grp == 0) {
    #pragma unroll
    for (int g = 0; g < 3; ++g) {
      const float* p = smem + (g * 256 + lt) * 13;
      t1[0][0]  += p[0]; t1[0][1]  += p[1]; t1[1][0]  += p[2];  t1[1][1]  += p[3];
      lda[0][0] += p[4]; lda[0][1] += p[5]; lda[1][0] += p[6];  lda[1][1] += p[7];
      dac[0][0] += p[8]; dac[0][1] += p[9]; dac[1][0] += p[10]; dac[1][1] += p[11];
    }
    const size_t zb = (size_t)z * BDIM * BDIM;
    #pragma unroll
    for (int ii = 0; ii < 2; ++ii) {
      const size_t o = zb + (size_t)(i0 + il + ii) * BDIM + j0 + jl;
      *(float2*)&t1p[o]  = make_float2(t1[ii][0],  t1[ii][1]);
      *(float2*)&ldap[o] = make_float2(lda[ii][0], lda[ii][1]);
      *(float2*)&dacp[o] = make_float2(dac[ii][0], dac[ii][1]);
    }
  }
}

// ---------------------------------------------------------------------------
// Kernel 3: combine z-partials -> sim, pdiag, per-row off-diag max (no atomics)
// ---------------------------------------------------------------------------
__global__ __launch_bounds__(256) void combine_kernel(
    const float* __restrict__ t1p, const float* __restrict__ ldap,
    const float* __restrict__ dacp, const float* __restrict__ ld,
    float* __restrict__ sim, float* __restrict__ pmaxf,
    float* __restrict__ pdiag) {
  const int i = blockIdx.x;
  const int t = threadIdx.x;
  const float l1 = ld[i];
  float rmax = 0.f;
  #pragma unroll
  for (int q = 0; q < 2; ++q) {
    const int j = t + q * 256;
    const size_t o = (size_t)i * BDIM + j;
    float t1 = 0.f, lda = 0.f, dac = 0.f;
    #pragma unroll
    for (int zz = 0; zz < 2; ++zz) {
      const size_t idx = (size_t)zz * BDIM * BDIM + o;
      t1 += t1p[idx]; lda += ldap[idx]; dac += dacp[idx];
    }
    const float bd = fmaf(0.125f, t1,
                          0.5f * (LN2 * lda - 0.5f * (l1 + ld[BDIM + j])));
    sim[o] = exp2f(bd * (-LOG2E / (float)DDIM));
    const float p = exp2f((2.0f * LOG2E) * dac);
    if (j == i) pdiag[i] = p;
    else        rmax = fmaxf(rmax, p);
  }
  __shared__ float red[4];
  const int wid = t >> 6, lane = t & 63;
  const float wm = wave_reduce_max(rmax);
  if (lane == 0) red[wid] = wm;
  __syncthreads();
  if (t == 0) pmaxf[i] = fmaxf(fmaxf(red[0], red[1]), fmaxf(red[2], red[3]));
}

// ---------------------------------------------------------------------------
// Kernel 4: per-row and per-column LSE of logits = scale*sim, plus diag.
// ---------------------------------------------------------------------------
__global__ __launch_bounds__(256) void lse_kernel(
    const float* __restrict__ sim, const float* __restrict__ lscale,
    float* __restrict__ lse_row, float* __restrict__ lse_col,
    float* __restrict__ dlog) {
  const int b = blockIdx.x;
  const int t = threadIdx.x;
  const float sc = *lscale;
  const float r0 = sc * sim[b * BDIM + t];
  const float r1 = sc * sim[b * BDIM + t + 256];
  const float c0 = sc * sim[t * BDIM + b];
  const float c1 = sc * sim[(t + 256) * BDIM + b];

  __shared__ float red[4];
  const int wid = t >> 6, lane = t & 63;

  float rm = wave_reduce_max(fmaxf(r0, r1));
  if (lane == 0) red[wid] = rm;
  __syncthreads();
  rm = fmaxf(fmaxf(red[0], red[1]), fmaxf(red[2], red[3]));
  __syncthreads();

  float cm = wave_reduce_max(fmaxf(c0, c1));
  if (lane == 0) red[wid] = cm;
  __syncthreads();
  cm = fmaxf(fmaxf(red[0], red[1]), fmaxf(red[2], red[3]));
  __syncthreads();

  float rs = wave_reduce_sum(exp2f((r0 - rm) * LOG2E) + exp2f((r1 - rm) * LOG2E));
  if (lane == 0) red[wid] = rs;
  __syncthreads();
  rs = red[0] + red[1] + red[2] + red[3];
  __syncthreads();

  float cs = wave_reduce_sum(exp2f((c0 - cm) * LOG2E) + exp2f((c1 - cm) * LOG2E));
  if (lane == 0) red[wid] = cs;
  __syncthreads();
  cs = red[0] + red[1] + red[2] + red[3];

  if (t == 0) {
    lse_row[b] = rm + LN2 * __log2f(rs);
    lse_col[b] = cm + LN2 * __log2f(cs);
    dlog[b]    = sc * sim[b * BDIM + b];
  }
}

// ---------------------------------------------------------------------------
// Kernel 5: final reductions -> 3 scalars.
// ---------------------------------------------------------------------------
__global__ __launch_bounds__(512) void final_kernel(
    const float* __restrict__ pdiag, const float* __restrict__ pmaxf,
    const float* __restrict__ mrow, const float* __restrict__ lse_row,
    const float* __restrict__ lse_col, const float* __restrict__ dlog,
    float* __restrict__ out) {
  const int t = threadIdx.x;  // 0..511
  const float pm = pmaxf[t];
  const float u  = exp2f(-(pdiag[t] / pm) * LOG2E);   // exp(-diag/negmax)
  const float as = 0.5f * (mrow[t] + mrow[BDIM + t]);

  float vals[6];
  vals[0] = u;
  vals[1] = u * u;
  vals[2] = as * as;
  vals[3] = u * as;
  vals[4] = lse_row[t] - dlog[t];
  vals[5] = lse_col[t] - dlog[t];

  __shared__ float red[6][8];
  const int wid = t >> 6, lane = t & 63;
  #pragma unroll
  for (int k = 0; k < 6; ++k) {
    const float v = wave_reduce_sum(vals[k]);
    if (lane == 0) red[k][wid] = v;
  }
  __syncthreads();
  if (t == 0) {
    float s[6];
    #pragma unroll
    for (int k = 0; k < 6; ++k) {
      float a = 0.f;
      #pragma unroll
      for (int w = 0; w < 8; ++w) a += red[k][w];
      s[k] = a;
    }
    const float mean_u = s[0] * (1.0f / BDIM);
    const float cosv = s[3] / fmaxf(sqrtf(s[1]) * sqrtf(s[2]), 1e-24f);
    out[0] = 0.5f * (s[4] + s[5]) * (1.0f / BDIM);  // loss_pro
    out[1] = 2.4f * (1.0f - cosv);                  // loss_rank * 2.4
    out[2] = 0.5f * mean_u;                         // var_loss
  }
}

extern "C" void kernel_launch(void* const* d_in, const int* in_sizes, int n_in,
                              void* d_out, int out_size, void* d_ws, size_t ws_size,
                              hipStream_t stream) {
  const float* mu1 = (const float*)d_in[0];
  const float* s1  = (const float*)d_in[1];
  const float* mu2 = (const float*)d_in[2];
  const float* s2  = (const float*)d_in[3];
  const float* lsc = (const float*)d_in[4];
  float* out = (float*)d_out;

  float* ws      = (float*)d_ws;
  float2* pA     = (float2*)ws;                       // 512*512 float2 (2MB)
  float2* pB     = pA + BDIM * DDIM;                  // 2MB
  float* sim     = (float*)(pB + BDIM * DDIM);        // 1MB
  float* t1p     = sim + BDIM * BDIM;                 // 2 * 1MB
  float* ldap    = t1p + 2 * BDIM * BDIM;             // 2 * 1MB
  float* dacp    = ldap + 2 * BDIM * BDIM;            // 2 * 1MB
  float* ld      = dacp + 2 * BDIM * BDIM;            // 2*512
  float* mrow    = ld + 2 * BDIM;                     // 2*512
  float* pmaxf   = mrow + 2 * BDIM;                   // 512
  float* pdiag   = pmaxf + BDIM;                      // 512
  float* lse_row = pdiag + BDIM;                      // 512
  float* lse_col = lse_row + BDIM;                    // 512
  float* dlog    = lse_col + BDIM;                    // 512

  prep_kernel<<<dim3(BDIM, 2), 256, 0, stream>>>(mu1, s1, mu2, s2, pA, pB,
                                                 ld, mrow);
  bd_kernel<<<dim3(16, 16, 2), 1024, 0, stream>>>(pA, pB, t1p, ldap, dacp);
  combine_kernel<<<BDIM, 256, 0, stream>>>(t1p, ldap, dacp, ld, sim, pmaxf,
                                           pdiag);
  lse_kernel<<<BDIM, 256, 0, stream>>>(sim, lsc, lse_row, lse_col, dlog);
  final_kernel<<<1, 512, 0, stream>>>(pdiag, pmaxf, mrow, lse_row, lse_col,
                                      dlog, out);
}